// Round 4
// baseline (254.500 us; speedup 1.0000x reference)
//
#include <hip/hip_runtime.h>

// GraphSAGE 3-layer forward: N=50000 nodes, E=800000 edges, F: 96->96->96->48
// out_i = relu( mean_{j in N(i)} h_j @ Wl + h_i @ Wr + b ), x3 layers.
//
// R16: column-plane-phased gather. R15's layers (~40us each) are bound by
// random 192B reads of the 9.6MB h buffer: per-XCD L2 (4MB) hits only ~42%,
// rest served by L3 at random-granule BW. Now h (and the mean buffer Mb)
// are stored as 3 planes [50016][32] bf16 (3.2MB each, < 4MB L2). Per layer:
// 3 slice-gather kernels (stream-serialized => global phase separation),
// each touching ONE plane -> L2-resident, 4 lanes fetch a neighbor's 64B
// slice as one coalesced granule; then an LDS-free MFMA GEMM kernel
// ([mean|h] @ [Wl;Wr] + bias + relu) with fully-coalesced A reads.
// Summation order per (node,col) is unchanged -> bit-identical output.
// build_a/build_b (atomic-free adjacency, R15) unchanged.

#define NNODES 50000
#define ZROW   50000        // sentinel row (all zeros) in each h buffer
#define PST    1600512      // plane stride in ushorts (50016 rows * 32 cols)
#define NEDGES 800000
#define CAP    64           // per-node adjacency capacity (max deg ~40 w.h.p.)
#define LSTR   72           // LDS cols stride in ushorts (144B -> bank-spread)
#define NBKT   512          // fine buckets
#define BKSZ   98           // nodes per bucket (512*98 >= 50000; max bucket 510)
#define NBKB   511          // phase-B grid (buckets actually populated)
#define EBA    400          // phase-A edge blocks
#define EPBA   2000         // edges per phase-A block (400*2000 = 800000)
#define SEGC   20           // slots per (ablock,bucket) cell (80B, 16B-aligned)
#define SGB    782          // slice-gather blocks (782*64 = 50048 >= 50000)
#define CVT_N8 600000       // 50000*96/8
#define CB 2344             // ceil(600000/256)
#define WTN 46080           // 2*96*192 + 48*192
#define WB 180              // ceil(46080/256)

typedef __attribute__((ext_vector_type(8))) short bf16x8;
typedef __attribute__((ext_vector_type(4))) float f32x4;

__device__ inline unsigned short f2bf(float f) {
    unsigned int u = __float_as_uint(f);
    unsigned int r = (u + 0x7fffu + ((u >> 16) & 1u)) >> 16;   // RNE
    return (unsigned short)r;
}
__device__ inline float bf2f_lo(unsigned int u) { return __uint_as_float(u << 16); }
__device__ inline float bf2f_hi(unsigned int u) { return __uint_as_float(u & 0xffff0000u); }

// ---------------- pass 1a: fine-bucket edges (LDS atomics) + converts ----------------
// blocks [0,EBA): edge bucket; [EBA,EBA+CB): x->bf16 (plane-sliced); next WB:
// WT prep; last 1: h0b sentinel rows (all 3 planes).
__global__ void build_a(const int* __restrict__ src, const int* __restrict__ dst,
                        unsigned int* __restrict__ region, unsigned char* __restrict__ cnta,
                        const float* __restrict__ x, unsigned short* __restrict__ h0b,
                        const float* __restrict__ Wl0, const float* __restrict__ Wr0,
                        const float* __restrict__ Wl1, const float* __restrict__ Wr1,
                        const float* __restrict__ Wl2, const float* __restrict__ Wr2,
                        unsigned short* __restrict__ WT0, unsigned short* __restrict__ WT1,
                        unsigned short* __restrict__ WT2) {
    int b = blockIdx.x;
    if (b < EBA) {
        __shared__ int hist[NBKT];
        const int t = threadIdx.x;
        for (int k = t; k < NBKT; k += 256) hist[k] = 0;
        __syncthreads();
        const int e0 = b * EPBA;
        for (int i = t; i < EPBA; i += 256) {
            int d = dst[e0 + i];
            int s = src[e0 + i];
            unsigned int bk = (unsigned int)d / 98u;       // magic-mul
            unsigned int rel = (unsigned int)d - bk * 98u; // 7 bits
            unsigned int val = (rel << 16) | (unsigned int)s;
            int r = atomicAdd(&hist[bk], 1);               // LDS atomic
            if (r < SEGC) region[((size_t)b * NBKT + bk) * SEGC + r] = val;
        }
        __syncthreads();
        for (int k = t; k < NBKT; k += 256)
            cnta[(size_t)k * EBA + b] = (unsigned char)min(hist[k], SEGC);
    } else if (b < EBA + CB) {
        long long t = (long long)(b - EBA) * 256 + threadIdx.x;
        if (t < CVT_N8) {
            int row = (int)(t / 12);
            int g = (int)(t - (long long)row * 12);        // col-group of 8
            const float4* pp = reinterpret_cast<const float4*>(x + (size_t)row * 96 + g * 8);
            float4 a = pp[0], c = pp[1];
            uint4 o;
            o.x = (unsigned)f2bf(a.x) | ((unsigned)f2bf(a.y) << 16);
            o.y = (unsigned)f2bf(a.z) | ((unsigned)f2bf(a.w) << 16);
            o.z = (unsigned)f2bf(c.x) | ((unsigned)f2bf(c.y) << 16);
            o.w = (unsigned)f2bf(c.z) | ((unsigned)f2bf(c.w) << 16);
            *reinterpret_cast<uint4*>(h0b + (size_t)(g >> 2) * PST + (size_t)row * 32
                                      + (g & 3) * 8) = o;
        }
    } else if (b < EBA + CB + WB) {
        int t = (b - EBA - CB) * 256 + threadIdx.x;
        if (t >= WTN) return;
        const float* Wl; const float* Wr; unsigned short* WT; int fout; int u;
        if (t < 18432)      { Wl = Wl0; Wr = Wr0; WT = WT0; fout = 96; u = t; }
        else if (t < 36864) { Wl = Wl1; Wr = Wr1; WT = WT1; fout = 96; u = t - 18432; }
        else                { Wl = Wl2; Wr = Wr2; WT = WT2; fout = 48; u = t - 36864; }
        int j = u / 192;
        int k = u - j * 192;
        float v = (k < 96) ? Wl[k * fout + j] : Wr[(k - 96) * fout + j];
        WT[u] = f2bf(v);
    } else {
        // zero h0b sentinel row in all 3 planes (12 uint4 stores)
        int t = threadIdx.x;
        if (t < 12) {
            uint4 z = make_uint4(0, 0, 0, 0);
            *reinterpret_cast<uint4*>(h0b + (size_t)(t >> 2) * PST + (size_t)ZROW * 32
                                      + (t & 3) * 8) = z;
        }
    }
}

// ---------------- pass 1b: per-bucket slotting via LDS atomics ----------------
__global__ __launch_bounds__(256) void build_b(const unsigned int* __restrict__ region,
                                               const unsigned char* __restrict__ cnta,
                                               int* __restrict__ deg,
                                               unsigned short* __restrict__ colu) {
    __shared__ unsigned char cnt_l[EBA];
    __shared__ int deg_l[BKSZ];
    __shared__ __attribute__((aligned(16))) unsigned short colu_l[BKSZ * CAP];
    const int k = blockIdx.x;           // bucket
    const int t = threadIdx.x;
    const int base_node = k * BKSZ;
    const int nn = min(BKSZ, NNODES - base_node);   // 98, last block 20
    for (int i = t; i < EBA; i += 256) cnt_l[i] = cnta[(size_t)k * EBA + i];
    if (t < BKSZ) deg_l[t] = 0;
    __syncthreads();

    for (int cb = t; cb < EBA; cb += 256) {
        const int c = cnt_l[cb];
        const unsigned int* cell = region + ((size_t)cb * NBKT + k) * SEGC;
        for (int j = 0; j < c; j += 4) {
            uint4 q = *reinterpret_cast<const uint4*>(cell + j);   // 16B-aligned (SEGC=20)
            unsigned int qq0 = q.x, qq1 = q.y, qq2 = q.z, qq3 = q.w;
            if (j + 0 < c) {
                int local = (int)(qq0 >> 16);
                int r = atomicAdd(&deg_l[local], 1);
                if (r < CAP) colu_l[local * CAP + r] = (unsigned short)(qq0 & 0xffffu);
            }
            if (j + 1 < c) {
                int local = (int)(qq1 >> 16);
                int r = atomicAdd(&deg_l[local], 1);
                if (r < CAP) colu_l[local * CAP + r] = (unsigned short)(qq1 & 0xffffu);
            }
            if (j + 2 < c) {
                int local = (int)(qq2 >> 16);
                int r = atomicAdd(&deg_l[local], 1);
                if (r < CAP) colu_l[local * CAP + r] = (unsigned short)(qq2 & 0xffffu);
            }
            if (j + 3 < c) {
                int local = (int)(qq3 >> 16);
                int r = atomicAdd(&deg_l[local], 1);
                if (r < CAP) colu_l[local * CAP + r] = (unsigned short)(qq3 & 0xffffu);
            }
        }
    }
    __syncthreads();

    for (int i = t; i < nn * (CAP / 8); i += 256) {
        *reinterpret_cast<uint4*>(colu + (size_t)base_node * CAP + i * 8) =
            *reinterpret_cast<const uint4*>(colu_l + i * 8);
    }
    if (t < nn) deg[base_node + t] = deg_l[t];
}

// ---------------- slice gather: mean of one 32-col plane ----------------
// Block = 64 nodes x 4 threads (8 cols each). Stage+sanitize 64*CAP slots in
// LDS; per thread: loop neighbors 8-wide, each neighbor's 64B plane slice is
// covered by the node's 4 lanes -> coalesced 64B granules from an L2-resident
// 3.2MB plane. Writes Mb plane p (bf16). Deterministic (fixed j order).
__global__ __launch_bounds__(256) void gather_slice(
    const unsigned short* __restrict__ hb,   // 3-plane sliced h
    const int* __restrict__ deg, const unsigned short* __restrict__ colu,
    unsigned short* __restrict__ Mb, int p) {
    __shared__ unsigned short cols[64 * LSTR];
    const int i0 = blockIdx.x * 64;
    const int t = threadIdx.x;
    const int nn = min(64, NNODES - i0);

#pragma unroll
    for (int q = 0; q < 4; ++q) {
        int item = t + q * 256;              // uint2 item = 4 slots
        int u4 = item * 4;
        int node = u4 >> 6;
        int slot = u4 & 63;
        uint2 v = *reinterpret_cast<const uint2*>(colu + (size_t)(i0 + node) * CAP + slot);
        int d = (node < nn) ? deg[i0 + node] : 0;
        unsigned int s0 = (slot + 0 < d) ? (v.x & 0xffffu) : ZROW;
        unsigned int s1 = (slot + 1 < d) ? (v.x >> 16)     : ZROW;
        unsigned int s2 = (slot + 2 < d) ? (v.y & 0xffffu) : ZROW;
        unsigned int s3 = (slot + 3 < d) ? (v.y >> 16)     : ZROW;
        uint2 o;
        o.x = s0 | (s1 << 16);
        o.y = s2 | (s3 << 16);
        *reinterpret_cast<uint2*>(&cols[node * LSTR + slot]) = o;
    }
    __syncthreads();

    const int nl = t >> 2;
    const int cg = t & 3;
    const unsigned short* hp = hb + (size_t)p * PST + cg * 8;
    const int d = (nl < nn) ? deg[i0 + nl] : 0;
    const int pd = (d + 7) & ~7;
    float a0 = 0.f, a1 = 0.f, a2 = 0.f, a3 = 0.f, a4 = 0.f, a5 = 0.f, a6 = 0.f, a7 = 0.f;
    for (int j = 0; j < pd; j += 8) {
        uint4 cu = *reinterpret_cast<const uint4*>(&cols[nl * LSTR + j]);
        int s0 = (int)(cu.x & 0xffffu), s1 = (int)(cu.x >> 16);
        int s2 = (int)(cu.y & 0xffffu), s3 = (int)(cu.y >> 16);
        int s4 = (int)(cu.z & 0xffffu), s5 = (int)(cu.z >> 16);
        int s6 = (int)(cu.w & 0xffffu), s7 = (int)(cu.w >> 16);
        uint4 u0 = *reinterpret_cast<const uint4*>(hp + (size_t)s0 * 32);
        uint4 u1 = *reinterpret_cast<const uint4*>(hp + (size_t)s1 * 32);
        uint4 u2 = *reinterpret_cast<const uint4*>(hp + (size_t)s2 * 32);
        uint4 u3 = *reinterpret_cast<const uint4*>(hp + (size_t)s3 * 32);
        uint4 u4 = *reinterpret_cast<const uint4*>(hp + (size_t)s4 * 32);
        uint4 u5 = *reinterpret_cast<const uint4*>(hp + (size_t)s5 * 32);
        uint4 u6 = *reinterpret_cast<const uint4*>(hp + (size_t)s6 * 32);
        uint4 u7 = *reinterpret_cast<const uint4*>(hp + (size_t)s7 * 32);
        a0 += bf2f_lo(u0.x) + bf2f_lo(u1.x) + bf2f_lo(u2.x) + bf2f_lo(u3.x)
            + bf2f_lo(u4.x) + bf2f_lo(u5.x) + bf2f_lo(u6.x) + bf2f_lo(u7.x);
        a1 += bf2f_hi(u0.x) + bf2f_hi(u1.x) + bf2f_hi(u2.x) + bf2f_hi(u3.x)
            + bf2f_hi(u4.x) + bf2f_hi(u5.x) + bf2f_hi(u6.x) + bf2f_hi(u7.x);
        a2 += bf2f_lo(u0.y) + bf2f_lo(u1.y) + bf2f_lo(u2.y) + bf2f_lo(u3.y)
            + bf2f_lo(u4.y) + bf2f_lo(u5.y) + bf2f_lo(u6.y) + bf2f_lo(u7.y);
        a3 += bf2f_hi(u0.y) + bf2f_hi(u1.y) + bf2f_hi(u2.y) + bf2f_hi(u3.y)
            + bf2f_hi(u4.y) + bf2f_hi(u5.y) + bf2f_hi(u6.y) + bf2f_hi(u7.y);
        a4 += bf2f_lo(u0.z) + bf2f_lo(u1.z) + bf2f_lo(u2.z) + bf2f_lo(u3.z)
            + bf2f_lo(u4.z) + bf2f_lo(u5.z) + bf2f_lo(u6.z) + bf2f_lo(u7.z);
        a5 += bf2f_hi(u0.z) + bf2f_hi(u1.z) + bf2f_hi(u2.z) + bf2f_hi(u3.z)
            + bf2f_hi(u4.z) + bf2f_hi(u5.z) + bf2f_hi(u6.z) + bf2f_hi(u7.z);
        a6 += bf2f_lo(u0.w) + bf2f_lo(u1.w) + bf2f_lo(u2.w) + bf2f_lo(u3.w)
            + bf2f_lo(u4.w) + bf2f_lo(u5.w) + bf2f_lo(u6.w) + bf2f_lo(u7.w);
        a7 += bf2f_hi(u0.w) + bf2f_hi(u1.w) + bf2f_hi(u2.w) + bf2f_hi(u3.w)
            + bf2f_hi(u4.w) + bf2f_hi(u5.w) + bf2f_hi(u6.w) + bf2f_hi(u7.w);
    }
    float inv = (d > 0) ? 1.0f / (float)d : 0.0f;
    uint4 o;
    o.x = (unsigned)f2bf(a0 * inv) | ((unsigned)f2bf(a1 * inv) << 16);
    o.y = (unsigned)f2bf(a2 * inv) | ((unsigned)f2bf(a3 * inv) << 16);
    o.z = (unsigned)f2bf(a4 * inv) | ((unsigned)f2bf(a5 * inv) << 16);
    o.w = (unsigned)f2bf(a6 * inv) | ((unsigned)f2bf(a7 * inv) << 16);
    if (nl < nn)
        *reinterpret_cast<uint4*>(Mb + (size_t)p * PST + (size_t)(i0 + nl) * 32 + cg * 8) = o;
}

// ---------------- dense MFMA GEMM: [mean|h] @ [Wl;Wr] + bias + relu ----------------
// No LDS. Block = 16 nodes, 4 waves; A-frags read fully-coalesced from the
// Mb / hb planes (64 lanes cover 16 rows x 64B of one plane per instr).
// A-frag (16x16x32 bf16): lane holds A[m=lane&15][k=(lane>>4)*8+0..7]
// B-frag: lane holds B[k][n=lane&15] -> WT[n][k] rows
// C/D: col=lane&15, row=(lane>>4)*4+reg  (verified layout, m89)
template <int NT, bool WRITE_BF16>
__global__ __launch_bounds__(256) void fused_gemm(
    const unsigned short* __restrict__ Mb, const unsigned short* __restrict__ hb,
    const unsigned short* __restrict__ WT,   // [16*NT][192]
    const float* __restrict__ bias,          // [16*NT]
    unsigned short* __restrict__ out_bf, float* __restrict__ out_f) {
    const int i0 = blockIdx.x * 16;
    const int t = threadIdx.x;

    if (WRITE_BF16 && blockIdx.x == 0 && t < 12) {
        uint4 z = make_uint4(0, 0, 0, 0);
        *reinterpret_cast<uint4*>(out_bf + (size_t)(t >> 2) * PST + (size_t)ZROW * 32
                                  + (t & 3) * 8) = z;
    }

    const int wave = t >> 6;
    const int lane = t & 63;
    const int m = lane & 15;
    const int kq = (lane >> 4) * 8;

    bf16x8 afr[6];
#pragma unroll
    for (int kk = 0; kk < 3; ++kk)
        afr[kk] = *reinterpret_cast<const bf16x8*>(Mb + (size_t)kk * PST
                                                   + (size_t)(i0 + m) * 32 + kq);
#pragma unroll
    for (int kk = 0; kk < 3; ++kk)
        afr[3 + kk] = *reinterpret_cast<const bf16x8*>(hb + (size_t)kk * PST
                                                       + (size_t)(i0 + m) * 32 + kq);

    const int r0 = (lane >> 4) * 4;
    for (int nt = wave; nt < NT; nt += 4) {
        f32x4 acc = {0.f, 0.f, 0.f, 0.f};
        const unsigned short* wrow = WT + (size_t)(nt * 16 + m) * 192 + kq;
#pragma unroll
        for (int kk = 0; kk < 6; ++kk) {
            bf16x8 bfr = *reinterpret_cast<const bf16x8*>(wrow + kk * 32);
            acc = __builtin_amdgcn_mfma_f32_16x16x32_bf16(afr[kk], bfr, acc, 0, 0, 0);
        }
        int colj = nt * 16 + m;
        float bv = bias[colj];
#pragma unroll
        for (int r = 0; r < 4; ++r) {
            float v = fmaxf(acc[r] + bv, 0.0f);
            int row = i0 + r0 + r;
            if (WRITE_BF16)
                out_bf[(size_t)(colj >> 5) * PST + (size_t)row * 32 + (colj & 31)] = f2bf(v);
            else
                out_f[(size_t)row * 48 + colj] = v;
        }
    }
}

extern "C" void kernel_launch(void* const* d_in, const int* in_sizes, int n_in,
                              void* d_out, int out_size, void* d_ws, size_t ws_size,
                              hipStream_t stream) {
    const float* x   = (const float*)d_in[0];
    const int*   ei  = (const int*)d_in[1];   // [2, E]: row0 = src, row1 = dst
    const float* Wl0 = (const float*)d_in[2];
    const float* Wr0 = (const float*)d_in[3];
    const float* b0  = (const float*)d_in[4];
    const float* Wl1 = (const float*)d_in[5];
    const float* Wr1 = (const float*)d_in[6];
    const float* b1  = (const float*)d_in[7];
    const float* Wl2 = (const float*)d_in[8];
    const float* Wr2 = (const float*)d_in[9];
    const float* b2  = (const float*)d_in[10];
    float* out = (float*)d_out;

    const int* src = ei;
    const int* dst = ei + NEDGES;

    // workspace layout (all offsets multiples of 64 B)
    char* p = (char*)d_ws;
    int* deg = (int*)p;                        p += (size_t)50176 * 4;        // 200 KB
    unsigned short* colu = (unsigned short*)p; p += (size_t)50176 * CAP * 2;  // 6.4 MB
    unsigned char* cnta = (unsigned char*)p;   p += (size_t)NBKT * EBA;       // 204800 B
    unsigned short* WT0 = (unsigned short*)p;  p += 96 * 192 * 2;
    unsigned short* WT1 = (unsigned short*)p;  p += 96 * 192 * 2;
    unsigned short* WT2 = (unsigned short*)p;  p += 48 * 192 * 2;
    unsigned short* h0b = (unsigned short*)p;  p += (size_t)3 * PST * 2 + 64; // 9.6 MB
    unsigned short* h1b = (unsigned short*)p;  p += (size_t)3 * PST * 2 + 64;
    unsigned short* h2b = (unsigned short*)p;  p += (size_t)3 * PST * 2 + 64;
    unsigned short* Mb  = (unsigned short*)p;  p += (size_t)3 * PST * 2 + 64;

    // region (EBA*NBKT*SEGC*4 = 16.38 MB) aliases h1b+h2b (19.2 MB): region is
    // dead after build_b; h1b/h2b are first written by the GEMM kernels after.
    unsigned int* region = (unsigned int*)h1b;

    // ---- phase A: fine-bucket edges + converts (one grid, LDS atomics only) ----
    build_a<<<EBA + CB + WB + 1, 256, 0, stream>>>(
        src, dst, region, cnta, x, h0b,
        Wl0, Wr0, Wl1, Wr1, Wl2, Wr2, WT0, WT1, WT2);

    // ---- phase B: one bucket per block, LDS-atomic slotting, coalesced dump ----
    build_b<<<NBKB, 256, 0, stream>>>(region, cnta, deg, colu);

    // ---- layers: 3 plane-phased slice gathers + 1 dense MFMA GEMM each ----
    const int GB = NNODES / 16;   // 3125 exact

    gather_slice<<<SGB, 256, 0, stream>>>(h0b, deg, colu, Mb, 0);
    gather_slice<<<SGB, 256, 0, stream>>>(h0b, deg, colu, Mb, 1);
    gather_slice<<<SGB, 256, 0, stream>>>(h0b, deg, colu, Mb, 2);
    fused_gemm<6, true><<<GB, 256, 0, stream>>>(Mb, h0b, WT0, b0, h1b, nullptr);

    gather_slice<<<SGB, 256, 0, stream>>>(h1b, deg, colu, Mb, 0);
    gather_slice<<<SGB, 256, 0, stream>>>(h1b, deg, colu, Mb, 1);
    gather_slice<<<SGB, 256, 0, stream>>>(h1b, deg, colu, Mb, 2);
    fused_gemm<6, true><<<GB, 256, 0, stream>>>(Mb, h1b, WT1, b1, h2b, nullptr);

    gather_slice<<<SGB, 256, 0, stream>>>(h2b, deg, colu, Mb, 0);
    gather_slice<<<SGB, 256, 0, stream>>>(h2b, deg, colu, Mb, 1);
    gather_slice<<<SGB, 256, 0, stream>>>(h2b, deg, colu, Mb, 2);
    fused_gemm<3, false><<<GB, 256, 0, stream>>>(Mb, h2b, WT2, b2, nullptr, out);
}

// Round 5
// 195.402 us; speedup vs baseline: 1.3024x; 1.3024x over previous
//
#include <hip/hip_runtime.h>

// GraphSAGE 3-layer forward: N=50000 nodes, E=800000 edges, F: 96->96->96->48
// out_i = relu( mean_{j in N(i)} h_j @ Wl + h_i @ Wr + b ), x3 layers.
//
// R17: revert to R15 structure (best verified, 200.4us) + two tweaks.
// R16's plane-phasing regressed (+54us): gather is load-ISSUE bound (~15us/
// layer of 16B scattered loads), so phase-splitting only multiplied fixed
// costs (12 dispatches, 3x colu staging, Mb round-trip). Tweaks here:
//  (1) build_a/build_b at 512 threads/block: 2x resident waves; build_b
//      becomes 1 cell/thread with an independent load burst (was 2 dependent
//      latency rounds at 2 waves/SIMD). Predict build ~24 -> ~12us.
//  (2) gather tail: 8-wide main over d&~7 + <=2 4-wide tail iters over
//      (d+3)&~3: sentinel waste 3.5 -> 1.5 loads/node (~9% fewer gathers).
// Everything else identical to R15.

#define NNODES 50000
#define ZROW   50000        // sentinel row (all zeros) in each h buffer
#define NEDGES 800000
#define CAP    64           // per-node adjacency capacity (max deg ~45 w.h.p.)
#define LSTR   72           // LDS cols stride in ushorts (144B -> bank-spread)
#define NBKT   512          // fine buckets
#define BKSZ   98           // nodes per bucket (512*98 >= 50000; max bucket 510)
#define NBKB   511          // phase-B grid (buckets actually populated)
#define EBA    400          // phase-A edge blocks
#define EPBA   2000         // edges per phase-A block (400*2000 = 800000)
#define SEGC   20           // slots per (ablock,bucket) cell (80B, 16B-aligned)
#define CVT_N8 600000       // 50000*96/8
#define CB 1172             // ceil(600000/512)
#define WTN 46080           // 2*96*192 + 48*192
#define WB 90               // ceil(46080/512)

typedef __attribute__((ext_vector_type(8))) short bf16x8;
typedef __attribute__((ext_vector_type(4))) float f32x4;

__device__ inline unsigned short f2bf(float f) {
    unsigned int u = __float_as_uint(f);
    unsigned int r = (u + 0x7fffu + ((u >> 16) & 1u)) >> 16;   // RNE
    return (unsigned short)r;
}
__device__ inline float bf2f_lo(unsigned int u) { return __uint_as_float(u << 16); }
__device__ inline float bf2f_hi(unsigned int u) { return __uint_as_float(u & 0xffff0000u); }

// ---------------- pass 1a: fine-bucket edges (LDS atomics) + converts ----------------
// 512 threads/block. blocks [0,EBA): edge bucket; [EBA,EBA+CB): x->bf16;
// next WB: WT prep; last 1: h0b sentinel.
__global__ __launch_bounds__(512) void build_a(
        const int* __restrict__ src, const int* __restrict__ dst,
        unsigned int* __restrict__ region, unsigned char* __restrict__ cnta,
        const float* __restrict__ x, unsigned short* __restrict__ h0b,
        const float* __restrict__ Wl0, const float* __restrict__ Wr0,
        const float* __restrict__ Wl1, const float* __restrict__ Wr1,
        const float* __restrict__ Wl2, const float* __restrict__ Wr2,
        unsigned short* __restrict__ WT0, unsigned short* __restrict__ WT1,
        unsigned short* __restrict__ WT2) {
    int b = blockIdx.x;
    if (b < EBA) {
        __shared__ int hist[NBKT];
        const int t = threadIdx.x;
        for (int k = t; k < NBKT; k += 512) hist[k] = 0;
        __syncthreads();
        const int e0 = b * EPBA;
        for (int i = t; i < EPBA; i += 512) {
            int d = dst[e0 + i];
            int s = src[e0 + i];
            unsigned int bk = (unsigned int)d / 98u;       // magic-mul
            unsigned int rel = (unsigned int)d - bk * 98u; // 7 bits
            unsigned int val = (rel << 16) | (unsigned int)s;
            int r = atomicAdd(&hist[bk], 1);               // LDS atomic
            if (r < SEGC) region[((size_t)b * NBKT + bk) * SEGC + r] = val;
        }
        __syncthreads();
        for (int k = t; k < NBKT; k += 512)
            cnta[(size_t)k * EBA + b] = (unsigned char)min(hist[k], SEGC);
    } else if (b < EBA + CB) {
        long long t = (long long)(b - EBA) * 512 + threadIdx.x;
        if (t < CVT_N8) {
            const float4* p = reinterpret_cast<const float4*>(x + t * 8);
            float4 a = p[0], c = p[1];
            uint4 o;
            o.x = (unsigned)f2bf(a.x) | ((unsigned)f2bf(a.y) << 16);
            o.y = (unsigned)f2bf(a.z) | ((unsigned)f2bf(a.w) << 16);
            o.z = (unsigned)f2bf(c.x) | ((unsigned)f2bf(c.y) << 16);
            o.w = (unsigned)f2bf(c.z) | ((unsigned)f2bf(c.w) << 16);
            *reinterpret_cast<uint4*>(h0b + t * 8) = o;
        }
    } else if (b < EBA + CB + WB) {
        int t = (b - EBA - CB) * 512 + threadIdx.x;
        if (t >= WTN) return;
        const float* Wl; const float* Wr; unsigned short* WT; int fout; int u;
        if (t < 18432)      { Wl = Wl0; Wr = Wr0; WT = WT0; fout = 96; u = t; }
        else if (t < 36864) { Wl = Wl1; Wr = Wr1; WT = WT1; fout = 96; u = t - 18432; }
        else                { Wl = Wl2; Wr = Wr2; WT = WT2; fout = 48; u = t - 36864; }
        int j = u / 192;
        int k = u - j * 192;
        float v = (k < 96) ? Wl[k * fout + j] : Wr[(k - 96) * fout + j];
        WT[u] = f2bf(v);
    } else {
        // zero the h0b sentinel row (h1b/h2b sentinels are zeroed by the layer
        // kernels that produce those buffers -- region aliases them here)
        int t = threadIdx.x;
        if (t < 12) {
            uint4 z = make_uint4(0, 0, 0, 0);
            *reinterpret_cast<uint4*>(h0b + (size_t)ZROW * 96 + t * 8) = z;
        }
    }
}

// ---------------- pass 1b: per-bucket slotting via LDS atomics ----------------
// 511 blocks x 512 threads; block k owns bucket k (98 nodes). One cell per
// thread (t<400): cnt read + <=5 independent uint4 loads issued as one burst,
// then LDS-atomic slotting into the 12.5KB LDS adjacency; coalesced dump.
__global__ __launch_bounds__(512) void build_b(const unsigned int* __restrict__ region,
                                               const unsigned char* __restrict__ cnta,
                                               int* __restrict__ deg,
                                               unsigned short* __restrict__ colu) {
    __shared__ unsigned char cnt_l[EBA];
    __shared__ int deg_l[BKSZ];
    __shared__ __attribute__((aligned(16))) unsigned short colu_l[BKSZ * CAP];
    const int k = blockIdx.x;           // bucket
    const int t = threadIdx.x;
    const int base_node = k * BKSZ;
    const int nn = min(BKSZ, NNODES - base_node);   // 98, last block 20
    for (int i = t; i < EBA; i += 512) cnt_l[i] = cnta[(size_t)k * EBA + i];
    if (t < BKSZ) deg_l[t] = 0;
    __syncthreads();

    for (int cb = t; cb < EBA; cb += 512) {
        const int c = cnt_l[cb];
        const unsigned int* cell = region + ((size_t)cb * NBKT + k) * SEGC;
        for (int j = 0; j < c; j += 4) {
            uint4 q = *reinterpret_cast<const uint4*>(cell + j);   // 16B-aligned (SEGC=20)
            unsigned int qq0 = q.x, qq1 = q.y, qq2 = q.z, qq3 = q.w;
            if (j + 0 < c) {
                int local = (int)(qq0 >> 16);
                int r = atomicAdd(&deg_l[local], 1);
                if (r < CAP) colu_l[local * CAP + r] = (unsigned short)(qq0 & 0xffffu);
            }
            if (j + 1 < c) {
                int local = (int)(qq1 >> 16);
                int r = atomicAdd(&deg_l[local], 1);
                if (r < CAP) colu_l[local * CAP + r] = (unsigned short)(qq1 & 0xffffu);
            }
            if (j + 2 < c) {
                int local = (int)(qq2 >> 16);
                int r = atomicAdd(&deg_l[local], 1);
                if (r < CAP) colu_l[local * CAP + r] = (unsigned short)(qq2 & 0xffffu);
            }
            if (j + 3 < c) {
                int local = (int)(qq3 >> 16);
                int r = atomicAdd(&deg_l[local], 1);
                if (r < CAP) colu_l[local * CAP + r] = (unsigned short)(qq3 & 0xffffu);
            }
        }
    }
    __syncthreads();

    // coalesced dump (uninit slots >= deg are sanitized by the layer kernel)
    for (int i = t; i < nn * (CAP / 8); i += 512) {
        *reinterpret_cast<uint4*>(colu + (size_t)base_node * CAP + i * 8) =
            *reinterpret_cast<const uint4*>(colu_l + i * 8);
    }
    if (t < nn) deg[base_node + t] = deg_l[t];
}

// ---------------- fused gather-mean + dual MFMA GEMM + bias + relu ----------------
// Block = 16 nodes, 256 threads. Stage 16*CAP ushort slots (2 KB) into LDS
// (stride LSTR, sanitized: slot>=deg -> ZROW). Threads 0..191 gather-mean
// (8-wide main + <=2 4-wide tail iters) into Asm; 4 waves run the K=192
// [mean|h] @ [Wl;Wr] MFMA, N-tiles strided across waves.
// A-frag (16x16x32 bf16): lane holds A[m=lane&15][k=(lane>>4)*8+0..7]
// B-frag: lane holds B[k=(lane>>4)*8+0..7][n=lane&15] -> WT[n][k] rows
// C/D: col=lane&15, row=(lane>>4)*4+reg  (verified layout, m89)
// When WRITE_BF16, block 0 also zeros the output buffer's sentinel row
// (consumed by the NEXT layer's gather; this kernel never reads it).
template <int NT, bool WRITE_BF16>
__global__ __launch_bounds__(256) void fused_layer(
    const unsigned short* __restrict__ hb,
    const int* __restrict__ deg, const unsigned short* __restrict__ colu,
    const unsigned short* __restrict__ WT,   // [16*NT][192]
    const float* __restrict__ bias,          // [16*NT]
    unsigned short* __restrict__ out_bf, float* __restrict__ out_f) {
    __shared__ unsigned short Asm[16][200];
    __shared__ unsigned short cols[16 * LSTR];
    const int i0 = blockIdx.x * 16;
    const int t = threadIdx.x;

    if (WRITE_BF16 && blockIdx.x == 0 && t < 12) {
        uint4 z = make_uint4(0, 0, 0, 0);
        *reinterpret_cast<uint4*>(out_bf + (size_t)ZROW * 96 + t * 8) = z;
    }

    // ---- stage + sanitize adjacency: 1024 ushorts, 4 per thread ----
    {
        int u4 = t * 4;                      // ushort index 0..1020
        int node = u4 >> 6;                  // CAP=64
        int slot = u4 & 63;
        uint2 v = *reinterpret_cast<const uint2*>(colu + (size_t)(i0 + node) * CAP + slot);
        int d = deg[i0 + node];
        unsigned int s0 = (slot + 0 < d) ? (v.x & 0xffffu) : ZROW;
        unsigned int s1 = (slot + 1 < d) ? (v.x >> 16)     : ZROW;
        unsigned int s2 = (slot + 2 < d) ? (v.y & 0xffffu) : ZROW;
        unsigned int s3 = (slot + 3 < d) ? (v.y >> 16)     : ZROW;
        uint2 o;
        o.x = s0 | (s1 << 16);
        o.y = s2 | (s3 << 16);
        *reinterpret_cast<uint2*>(&cols[node * LSTR + slot]) = o;
    }
    __syncthreads();

    if (t < 192) {
        const int nl = t / 12;
        const int c = (t - nl * 12) * 8;
        const int d = deg[i0 + nl];
        const int d8 = d & ~7;               // full 8-groups
        const int pd4 = (d + 3) & ~3;        // 4-padded end (<=2 tail iters)
        float a0 = 0.f, a1 = 0.f, a2 = 0.f, a3 = 0.f, a4 = 0.f, a5 = 0.f, a6 = 0.f, a7 = 0.f;
        int j = 0;
        for (; j < d8; j += 8) {
            uint4 cu = *reinterpret_cast<const uint4*>(&cols[nl * LSTR + j]);
            int s0 = (int)(cu.x & 0xffffu), s1 = (int)(cu.x >> 16);
            int s2 = (int)(cu.y & 0xffffu), s3 = (int)(cu.y >> 16);
            int s4 = (int)(cu.z & 0xffffu), s5 = (int)(cu.z >> 16);
            int s6 = (int)(cu.w & 0xffffu), s7 = (int)(cu.w >> 16);
            uint4 u0 = *reinterpret_cast<const uint4*>(hb + (size_t)s0 * 96 + c);
            uint4 u1 = *reinterpret_cast<const uint4*>(hb + (size_t)s1 * 96 + c);
            uint4 u2 = *reinterpret_cast<const uint4*>(hb + (size_t)s2 * 96 + c);
            uint4 u3 = *reinterpret_cast<const uint4*>(hb + (size_t)s3 * 96 + c);
            uint4 u4 = *reinterpret_cast<const uint4*>(hb + (size_t)s4 * 96 + c);
            uint4 u5 = *reinterpret_cast<const uint4*>(hb + (size_t)s5 * 96 + c);
            uint4 u6 = *reinterpret_cast<const uint4*>(hb + (size_t)s6 * 96 + c);
            uint4 u7 = *reinterpret_cast<const uint4*>(hb + (size_t)s7 * 96 + c);
            a0 += bf2f_lo(u0.x) + bf2f_lo(u1.x) + bf2f_lo(u2.x) + bf2f_lo(u3.x)
                + bf2f_lo(u4.x) + bf2f_lo(u5.x) + bf2f_lo(u6.x) + bf2f_lo(u7.x);
            a1 += bf2f_hi(u0.x) + bf2f_hi(u1.x) + bf2f_hi(u2.x) + bf2f_hi(u3.x)
                + bf2f_hi(u4.x) + bf2f_hi(u5.x) + bf2f_hi(u6.x) + bf2f_hi(u7.x);
            a2 += bf2f_lo(u0.y) + bf2f_lo(u1.y) + bf2f_lo(u2.y) + bf2f_lo(u3.y)
                + bf2f_lo(u4.y) + bf2f_lo(u5.y) + bf2f_lo(u6.y) + bf2f_lo(u7.y);
            a3 += bf2f_hi(u0.y) + bf2f_hi(u1.y) + bf2f_hi(u2.y) + bf2f_hi(u3.y)
                + bf2f_hi(u4.y) + bf2f_hi(u5.y) + bf2f_hi(u6.y) + bf2f_hi(u7.y);
            a4 += bf2f_lo(u0.z) + bf2f_lo(u1.z) + bf2f_lo(u2.z) + bf2f_lo(u3.z)
                + bf2f_lo(u4.z) + bf2f_lo(u5.z) + bf2f_lo(u6.z) + bf2f_lo(u7.z);
            a5 += bf2f_hi(u0.z) + bf2f_hi(u1.z) + bf2f_hi(u2.z) + bf2f_hi(u3.z)
                + bf2f_hi(u4.z) + bf2f_hi(u5.z) + bf2f_hi(u6.z) + bf2f_hi(u7.z);
            a6 += bf2f_lo(u0.w) + bf2f_lo(u1.w) + bf2f_lo(u2.w) + bf2f_lo(u3.w)
                + bf2f_lo(u4.w) + bf2f_lo(u5.w) + bf2f_lo(u6.w) + bf2f_lo(u7.w);
            a7 += bf2f_hi(u0.w) + bf2f_hi(u1.w) + bf2f_hi(u2.w) + bf2f_hi(u3.w)
                + bf2f_hi(u4.w) + bf2f_hi(u5.w) + bf2f_hi(u6.w) + bf2f_hi(u7.w);
        }
        for (; j < pd4; j += 4) {            // 4-wide tail (sanitized -> ZROW)
            uint2 cu = *reinterpret_cast<const uint2*>(&cols[nl * LSTR + j]);
            int s0 = (int)(cu.x & 0xffffu), s1 = (int)(cu.x >> 16);
            int s2 = (int)(cu.y & 0xffffu), s3 = (int)(cu.y >> 16);
            uint4 u0 = *reinterpret_cast<const uint4*>(hb + (size_t)s0 * 96 + c);
            uint4 u1 = *reinterpret_cast<const uint4*>(hb + (size_t)s1 * 96 + c);
            uint4 u2 = *reinterpret_cast<const uint4*>(hb + (size_t)s2 * 96 + c);
            uint4 u3 = *reinterpret_cast<const uint4*>(hb + (size_t)s3 * 96 + c);
            a0 += bf2f_lo(u0.x) + bf2f_lo(u1.x) + bf2f_lo(u2.x) + bf2f_lo(u3.x);
            a1 += bf2f_hi(u0.x) + bf2f_hi(u1.x) + bf2f_hi(u2.x) + bf2f_hi(u3.x);
            a2 += bf2f_lo(u0.y) + bf2f_lo(u1.y) + bf2f_lo(u2.y) + bf2f_lo(u3.y);
            a3 += bf2f_hi(u0.y) + bf2f_hi(u1.y) + bf2f_hi(u2.y) + bf2f_hi(u3.y);
            a4 += bf2f_lo(u0.z) + bf2f_lo(u1.z) + bf2f_lo(u2.z) + bf2f_lo(u3.z);
            a5 += bf2f_hi(u0.z) + bf2f_hi(u1.z) + bf2f_hi(u2.z) + bf2f_hi(u3.z);
            a6 += bf2f_lo(u0.w) + bf2f_lo(u1.w) + bf2f_lo(u2.w) + bf2f_lo(u3.w);
            a7 += bf2f_hi(u0.w) + bf2f_hi(u1.w) + bf2f_hi(u2.w) + bf2f_hi(u3.w);
        }
        float inv = (d > 0) ? 1.0f / (float)d : 0.0f;
        uint4 o;
        o.x = (unsigned)f2bf(a0 * inv) | ((unsigned)f2bf(a1 * inv) << 16);
        o.y = (unsigned)f2bf(a2 * inv) | ((unsigned)f2bf(a3 * inv) << 16);
        o.z = (unsigned)f2bf(a4 * inv) | ((unsigned)f2bf(a5 * inv) << 16);
        o.w = (unsigned)f2bf(a6 * inv) | ((unsigned)f2bf(a7 * inv) << 16);
        *reinterpret_cast<uint4*>(&Asm[nl][c]) = o;
    }
    __syncthreads();

    const int wave = t >> 6;
    const int lane = t & 63;
    const int m = lane & 15;
    const int kq = (lane >> 4) * 8;

    bf16x8 afr[6];
#pragma unroll
    for (int kk = 0; kk < 3; ++kk)
        afr[kk] = *reinterpret_cast<const bf16x8*>(&Asm[m][kq + kk * 32]);
    const unsigned short* hrow = hb + (size_t)(i0 + m) * 96 + kq;
#pragma unroll
    for (int kk = 0; kk < 3; ++kk)
        afr[3 + kk] = *reinterpret_cast<const bf16x8*>(hrow + kk * 32);

    const int r0 = (lane >> 4) * 4;
    for (int nt = wave; nt < NT; nt += 4) {
        f32x4 acc = {0.f, 0.f, 0.f, 0.f};
        const unsigned short* wrow = WT + (size_t)(nt * 16 + m) * 192 + kq;
#pragma unroll
        for (int kk = 0; kk < 6; ++kk) {
            bf16x8 bfr = *reinterpret_cast<const bf16x8*>(wrow + kk * 32);
            acc = __builtin_amdgcn_mfma_f32_16x16x32_bf16(afr[kk], bfr, acc, 0, 0, 0);
        }
        int colj = nt * 16 + m;
        float bv = bias[colj];
#pragma unroll
        for (int r = 0; r < 4; ++r) {
            float v = fmaxf(acc[r] + bv, 0.0f);
            size_t oi = (size_t)(i0 + r0 + r) * (16 * NT) + colj;
            if (WRITE_BF16) out_bf[oi] = f2bf(v);
            else            out_f[oi] = v;
        }
    }
}

extern "C" void kernel_launch(void* const* d_in, const int* in_sizes, int n_in,
                              void* d_out, int out_size, void* d_ws, size_t ws_size,
                              hipStream_t stream) {
    const float* x   = (const float*)d_in[0];
    const int*   ei  = (const int*)d_in[1];   // [2, E]: row0 = src, row1 = dst
    const float* Wl0 = (const float*)d_in[2];
    const float* Wr0 = (const float*)d_in[3];
    const float* b0  = (const float*)d_in[4];
    const float* Wl1 = (const float*)d_in[5];
    const float* Wr1 = (const float*)d_in[6];
    const float* b1  = (const float*)d_in[7];
    const float* Wl2 = (const float*)d_in[8];
    const float* Wr2 = (const float*)d_in[9];
    const float* b2  = (const float*)d_in[10];
    float* out = (float*)d_out;

    const int* src = ei;
    const int* dst = ei + NEDGES;

    // workspace layout (all offsets multiples of 64 B)
    char* p = (char*)d_ws;
    int* deg = (int*)p;                        p += (size_t)50176 * 4;        // 200 KB
    unsigned short* colu = (unsigned short*)p; p += (size_t)50176 * CAP * 2;  // 6.4 MB
    unsigned char* cnta = (unsigned char*)p;   p += (size_t)NBKT * EBA;       // 204800 B
    unsigned short* WT0 = (unsigned short*)p;  p += 96 * 192 * 2;
    unsigned short* WT1 = (unsigned short*)p;  p += 96 * 192 * 2;
    unsigned short* WT2 = (unsigned short*)p;  p += 48 * 192 * 2;
    unsigned short* h0b = (unsigned short*)p;  p += (size_t)(NNODES + 1) * 96 * 2 + 64;
    unsigned short* h1b = (unsigned short*)p;  p += (size_t)(NNODES + 1) * 96 * 2 + 64;
    unsigned short* h2b = (unsigned short*)p;  p += (size_t)(NNODES + 1) * 96 * 2 + 64;

    // region (EBA*NBKT*SEGC*4 = 16.38 MB) aliases h1b+h2b (19.2 MB): region is
    // dead after build_b; h1b/h2b are first written by the layer kernels after.
    unsigned int* region = (unsigned int*)h1b;

    // ---- phase A: fine-bucket edges + converts (one grid, LDS atomics only) ----
    build_a<<<EBA + CB + WB + 1, 512, 0, stream>>>(
        src, dst, region, cnta, x, h0b,
        Wl0, Wr0, Wl1, Wr1, Wl2, Wr2, WT0, WT1, WT2);

    // ---- phase B: one bucket per block, LDS-atomic slotting, coalesced dump ----
    build_b<<<NBKB, 512, 0, stream>>>(region, cnta, deg, colu);

    // ---- layers (fused gather + MFMA), 16 nodes / 256 threads per block ----
    const int LB = NNODES / 16;   // 3125 exact
    fused_layer<6, true><<<LB, 256, 0, stream>>>(h0b, deg, colu, WT0, b0, h1b, nullptr);
    fused_layer<6, true><<<LB, 256, 0, stream>>>(h1b, deg, colu, WT1, b1, h2b, nullptr);
    fused_layer<3, false><<<LB, 256, 0, stream>>>(h2b, deg, colu, WT2, b2, nullptr, out);
}

// Round 6
// 190.267 us; speedup vs baseline: 1.3376x; 1.0270x over previous
//
#include <hip/hip_runtime.h>

// GraphSAGE 3-layer forward: N=50000 nodes, E=800000 edges, F: 96->96->96->48
// out_i = relu( mean_{j in N(i)} h_j @ Wl + h_i @ Wr + b ), x3 layers.
//
// R18: R17 structure + layer-2 "gather-after-transform". mean(h)@Wl2 ==
// mean(h@Wl2), and Wl2 maps 96->48, so gathering Y2 = h2@Wl2 (bf16 [N][48],
// 96B/row) halves layer-2's per-edge bytes AND load instructions (12->6
// 16B loads/edge; L3 random share ~90->45MB). Y2 is computed inside layer
// 1's kernel: after the h2 tile is produced, a 3-MFMA-per-wave epilogue
// (A from LDS-staged h2 tile, B = Wl2^T) writes Y2. fused_final gathers
// Y2-mean into LDS (f32) and adds the h2@Wr2 self-term via K=96 MFMA.
// build_a/build_b (atomic-free adjacency, 512 thr) unchanged from R17.

#define NNODES 50000
#define ZROW   50000        // sentinel row (all zeros) in h / Y2 buffers
#define NEDGES 800000
#define CAP    64           // per-node adjacency capacity (max deg ~45 w.h.p.)
#define LSTR   72           // LDS cols stride in ushorts (144B -> bank-spread)
#define NBKT   512          // fine buckets
#define BKSZ   98           // nodes per bucket (512*98 >= 50000; max bucket 510)
#define NBKB   511          // phase-B grid (buckets actually populated)
#define EBA    400          // phase-A edge blocks
#define EPBA   2000         // edges per phase-A block (400*2000 = 800000)
#define SEGC   20           // slots per (ablock,bucket) cell (80B, 16B-aligned)
#define CVT_N8 600000       // 50000*96/8
#define CB 1172             // ceil(600000/512)
#define WTN 46080           // 2*96*192 + 48*96 + 48*96 (same total as before)
#define WB 90               // ceil(46080/512)

typedef __attribute__((ext_vector_type(8))) short bf16x8;
typedef __attribute__((ext_vector_type(4))) float f32x4;

__device__ inline unsigned short f2bf(float f) {
    unsigned int u = __float_as_uint(f);
    unsigned int r = (u + 0x7fffu + ((u >> 16) & 1u)) >> 16;   // RNE
    return (unsigned short)r;
}
__device__ inline float bf2f_lo(unsigned int u) { return __uint_as_float(u << 16); }
__device__ inline float bf2f_hi(unsigned int u) { return __uint_as_float(u & 0xffff0000u); }

// ---------------- pass 1a: fine-bucket edges (LDS atomics) + converts ----------------
// 512 threads/block. blocks [0,EBA): edge bucket; [EBA,EBA+CB): x->bf16;
// next WB: WT prep (WT0, WT1, WT2l, WT2r); last 1: h0b sentinel.
__global__ __launch_bounds__(512) void build_a(
        const int* __restrict__ src, const int* __restrict__ dst,
        unsigned int* __restrict__ region, unsigned char* __restrict__ cnta,
        const float* __restrict__ x, unsigned short* __restrict__ h0b,
        const float* __restrict__ Wl0, const float* __restrict__ Wr0,
        const float* __restrict__ Wl1, const float* __restrict__ Wr1,
        const float* __restrict__ Wl2, const float* __restrict__ Wr2,
        unsigned short* __restrict__ WT0, unsigned short* __restrict__ WT1,
        unsigned short* __restrict__ WT2l, unsigned short* __restrict__ WT2r) {
    int b = blockIdx.x;
    if (b < EBA) {
        __shared__ int hist[NBKT];
        const int t = threadIdx.x;
        for (int k = t; k < NBKT; k += 512) hist[k] = 0;
        __syncthreads();
        const int e0 = b * EPBA;
        for (int i = t; i < EPBA; i += 512) {
            int d = dst[e0 + i];
            int s = src[e0 + i];
            unsigned int bk = (unsigned int)d / 98u;       // magic-mul
            unsigned int rel = (unsigned int)d - bk * 98u; // 7 bits
            unsigned int val = (rel << 16) | (unsigned int)s;
            int r = atomicAdd(&hist[bk], 1);               // LDS atomic
            if (r < SEGC) region[((size_t)b * NBKT + bk) * SEGC + r] = val;
        }
        __syncthreads();
        for (int k = t; k < NBKT; k += 512)
            cnta[(size_t)k * EBA + b] = (unsigned char)min(hist[k], SEGC);
    } else if (b < EBA + CB) {
        long long t = (long long)(b - EBA) * 512 + threadIdx.x;
        if (t < CVT_N8) {
            const float4* p = reinterpret_cast<const float4*>(x + t * 8);
            float4 a = p[0], c = p[1];
            uint4 o;
            o.x = (unsigned)f2bf(a.x) | ((unsigned)f2bf(a.y) << 16);
            o.y = (unsigned)f2bf(a.z) | ((unsigned)f2bf(a.w) << 16);
            o.z = (unsigned)f2bf(c.x) | ((unsigned)f2bf(c.y) << 16);
            o.w = (unsigned)f2bf(c.z) | ((unsigned)f2bf(c.w) << 16);
            *reinterpret_cast<uint4*>(h0b + t * 8) = o;
        }
    } else if (b < EBA + CB + WB) {
        int t = (b - EBA - CB) * 512 + threadIdx.x;
        if (t >= WTN) return;
        if (t < 18432) {                     // WT0 [96][192] = [Wl0;Wr0]^T
            int u = t; int j = u / 192; int k = u - j * 192;
            float v = (k < 96) ? Wl0[k * 96 + j] : Wr0[(k - 96) * 96 + j];
            WT0[u] = f2bf(v);
        } else if (t < 36864) {              // WT1 [96][192]
            int u = t - 18432; int j = u / 192; int k = u - j * 192;
            float v = (k < 96) ? Wl1[k * 96 + j] : Wr1[(k - 96) * 96 + j];
            WT1[u] = f2bf(v);
        } else if (t < 41472) {              // WT2l [48][96] = Wl2^T
            int u = t - 36864; int j = u / 96; int k = u - j * 96;
            WT2l[u] = f2bf(Wl2[k * 48 + j]);
        } else {                             // WT2r [48][96] = Wr2^T
            int u = t - 41472; int j = u / 96; int k = u - j * 96;
            WT2r[u] = f2bf(Wr2[k * 48 + j]);
        }
    } else {
        // zero the h0b sentinel row (h1b/h2b/Y2b sentinels are zeroed by the
        // layer kernels that produce those buffers -- region aliases h1b/h2b)
        int t = threadIdx.x;
        if (t < 12) {
            uint4 z = make_uint4(0, 0, 0, 0);
            *reinterpret_cast<uint4*>(h0b + (size_t)ZROW * 96 + t * 8) = z;
        }
    }
}

// ---------------- pass 1b: per-bucket slotting via LDS atomics ----------------
__global__ __launch_bounds__(512) void build_b(const unsigned int* __restrict__ region,
                                               const unsigned char* __restrict__ cnta,
                                               int* __restrict__ deg,
                                               unsigned short* __restrict__ colu) {
    __shared__ unsigned char cnt_l[EBA];
    __shared__ int deg_l[BKSZ];
    __shared__ __attribute__((aligned(16))) unsigned short colu_l[BKSZ * CAP];
    const int k = blockIdx.x;           // bucket
    const int t = threadIdx.x;
    const int base_node = k * BKSZ;
    const int nn = min(BKSZ, NNODES - base_node);   // 98, last block 20
    for (int i = t; i < EBA; i += 512) cnt_l[i] = cnta[(size_t)k * EBA + i];
    if (t < BKSZ) deg_l[t] = 0;
    __syncthreads();

    for (int cb = t; cb < EBA; cb += 512) {
        const int c = cnt_l[cb];
        const unsigned int* cell = region + ((size_t)cb * NBKT + k) * SEGC;
        for (int j = 0; j < c; j += 4) {
            uint4 q = *reinterpret_cast<const uint4*>(cell + j);   // 16B-aligned (SEGC=20)
            unsigned int qq0 = q.x, qq1 = q.y, qq2 = q.z, qq3 = q.w;
            if (j + 0 < c) {
                int local = (int)(qq0 >> 16);
                int r = atomicAdd(&deg_l[local], 1);
                if (r < CAP) colu_l[local * CAP + r] = (unsigned short)(qq0 & 0xffffu);
            }
            if (j + 1 < c) {
                int local = (int)(qq1 >> 16);
                int r = atomicAdd(&deg_l[local], 1);
                if (r < CAP) colu_l[local * CAP + r] = (unsigned short)(qq1 & 0xffffu);
            }
            if (j + 2 < c) {
                int local = (int)(qq2 >> 16);
                int r = atomicAdd(&deg_l[local], 1);
                if (r < CAP) colu_l[local * CAP + r] = (unsigned short)(qq2 & 0xffffu);
            }
            if (j + 3 < c) {
                int local = (int)(qq3 >> 16);
                int r = atomicAdd(&deg_l[local], 1);
                if (r < CAP) colu_l[local * CAP + r] = (unsigned short)(qq3 & 0xffffu);
            }
        }
    }
    __syncthreads();

    // coalesced dump (uninit slots >= deg are sanitized by the layer kernel)
    for (int i = t; i < nn * (CAP / 8); i += 512) {
        *reinterpret_cast<uint4*>(colu + (size_t)base_node * CAP + i * 8) =
            *reinterpret_cast<const uint4*>(colu_l + i * 8);
    }
    if (t < nn) deg[base_node + t] = deg_l[t];
}

// ---------------- fused gather-mean + dual MFMA GEMM + bias + relu ----------------
// Block = 16 nodes, 256 threads. NT=6 (96 out cols, bf16 out). If Y2EP, an
// epilogue re-stages the h2 tile in Asm (dead after A-frag loads) and runs a
// 3-MFMA-per-wave K=96 GEMM vs WT2l to emit Y2 = h2 @ Wl2 (bf16 [N][48]).
// A-frag (16x16x32 bf16): lane holds A[m=lane&15][k=(lane>>4)*8+0..7]
// B-frag: lane holds B[k=(lane>>4)*8+0..7][n=lane&15] -> WT[n][k] rows
// C/D: col=lane&15, row=(lane>>4)*4+reg  (verified layout, m89)
template <int NT, bool Y2EP>
__global__ __launch_bounds__(256) void fused_layer(
    const unsigned short* __restrict__ hb,
    const int* __restrict__ deg, const unsigned short* __restrict__ colu,
    const unsigned short* __restrict__ WT,   // [16*NT][192]
    const float* __restrict__ bias,          // [16*NT]
    unsigned short* __restrict__ out_bf,
    const unsigned short* __restrict__ WT2l, // [48][96] (Y2EP only)
    unsigned short* __restrict__ Y2b) {      // [50001][48] (Y2EP only)
    __shared__ unsigned short Asm[16][200];
    __shared__ unsigned short cols[16 * LSTR];
    const int i0 = blockIdx.x * 16;
    const int t = threadIdx.x;

    if (blockIdx.x == 0) {
        if (t < 12) {   // zero out_bf sentinel row (read by next layer's gather)
            uint4 z = make_uint4(0, 0, 0, 0);
            *reinterpret_cast<uint4*>(out_bf + (size_t)ZROW * 96 + t * 8) = z;
        }
        if (Y2EP && t >= 16 && t < 22) {   // zero Y2b sentinel (48 ushorts)
            uint4 z = make_uint4(0, 0, 0, 0);
            *reinterpret_cast<uint4*>(Y2b + (size_t)ZROW * 48 + (t - 16) * 8) = z;
        }
    }

    // ---- stage + sanitize adjacency: 1024 ushorts, 4 per thread ----
    {
        int u4 = t * 4;                      // ushort index 0..1020
        int node = u4 >> 6;                  // CAP=64
        int slot = u4 & 63;
        uint2 v = *reinterpret_cast<const uint2*>(colu + (size_t)(i0 + node) * CAP + slot);
        int d = deg[i0 + node];
        unsigned int s0 = (slot + 0 < d) ? (v.x & 0xffffu) : ZROW;
        unsigned int s1 = (slot + 1 < d) ? (v.x >> 16)     : ZROW;
        unsigned int s2 = (slot + 2 < d) ? (v.y & 0xffffu) : ZROW;
        unsigned int s3 = (slot + 3 < d) ? (v.y >> 16)     : ZROW;
        uint2 o;
        o.x = s0 | (s1 << 16);
        o.y = s2 | (s3 << 16);
        *reinterpret_cast<uint2*>(&cols[node * LSTR + slot]) = o;
    }
    __syncthreads();

    if (t < 192) {
        const int nl = t / 12;
        const int c = (t - nl * 12) * 8;
        const int d = deg[i0 + nl];
        const int d8 = d & ~7;               // full 8-groups
        const int pd4 = (d + 3) & ~3;        // 4-padded end (<=2 tail iters)
        float a0 = 0.f, a1 = 0.f, a2 = 0.f, a3 = 0.f, a4 = 0.f, a5 = 0.f, a6 = 0.f, a7 = 0.f;
        int j = 0;
        for (; j < d8; j += 8) {
            uint4 cu = *reinterpret_cast<const uint4*>(&cols[nl * LSTR + j]);
            int s0 = (int)(cu.x & 0xffffu), s1 = (int)(cu.x >> 16);
            int s2 = (int)(cu.y & 0xffffu), s3 = (int)(cu.y >> 16);
            int s4 = (int)(cu.z & 0xffffu), s5 = (int)(cu.z >> 16);
            int s6 = (int)(cu.w & 0xffffu), s7 = (int)(cu.w >> 16);
            uint4 u0 = *reinterpret_cast<const uint4*>(hb + (size_t)s0 * 96 + c);
            uint4 u1 = *reinterpret_cast<const uint4*>(hb + (size_t)s1 * 96 + c);
            uint4 u2 = *reinterpret_cast<const uint4*>(hb + (size_t)s2 * 96 + c);
            uint4 u3 = *reinterpret_cast<const uint4*>(hb + (size_t)s3 * 96 + c);
            uint4 u4 = *reinterpret_cast<const uint4*>(hb + (size_t)s4 * 96 + c);
            uint4 u5 = *reinterpret_cast<const uint4*>(hb + (size_t)s5 * 96 + c);
            uint4 u6 = *reinterpret_cast<const uint4*>(hb + (size_t)s6 * 96 + c);
            uint4 u7 = *reinterpret_cast<const uint4*>(hb + (size_t)s7 * 96 + c);
            a0 += bf2f_lo(u0.x) + bf2f_lo(u1.x) + bf2f_lo(u2.x) + bf2f_lo(u3.x)
                + bf2f_lo(u4.x) + bf2f_lo(u5.x) + bf2f_lo(u6.x) + bf2f_lo(u7.x);
            a1 += bf2f_hi(u0.x) + bf2f_hi(u1.x) + bf2f_hi(u2.x) + bf2f_hi(u3.x)
                + bf2f_hi(u4.x) + bf2f_hi(u5.x) + bf2f_hi(u6.x) + bf2f_hi(u7.x);
            a2 += bf2f_lo(u0.y) + bf2f_lo(u1.y) + bf2f_lo(u2.y) + bf2f_lo(u3.y)
                + bf2f_lo(u4.y) + bf2f_lo(u5.y) + bf2f_lo(u6.y) + bf2f_lo(u7.y);
            a3 += bf2f_hi(u0.y) + bf2f_hi(u1.y) + bf2f_hi(u2.y) + bf2f_hi(u3.y)
                + bf2f_hi(u4.y) + bf2f_hi(u5.y) + bf2f_hi(u6.y) + bf2f_hi(u7.y);
            a4 += bf2f_lo(u0.z) + bf2f_lo(u1.z) + bf2f_lo(u2.z) + bf2f_lo(u3.z)
                + bf2f_lo(u4.z) + bf2f_lo(u5.z) + bf2f_lo(u6.z) + bf2f_lo(u7.z);
            a5 += bf2f_hi(u0.z) + bf2f_hi(u1.z) + bf2f_hi(u2.z) + bf2f_hi(u3.z)
                + bf2f_hi(u4.z) + bf2f_hi(u5.z) + bf2f_hi(u6.z) + bf2f_hi(u7.z);
            a6 += bf2f_lo(u0.w) + bf2f_lo(u1.w) + bf2f_lo(u2.w) + bf2f_lo(u3.w)
                + bf2f_lo(u4.w) + bf2f_lo(u5.w) + bf2f_lo(u6.w) + bf2f_lo(u7.w);
            a7 += bf2f_hi(u0.w) + bf2f_hi(u1.w) + bf2f_hi(u2.w) + bf2f_hi(u3.w)
                + bf2f_hi(u4.w) + bf2f_hi(u5.w) + bf2f_hi(u6.w) + bf2f_hi(u7.w);
        }
        for (; j < pd4; j += 4) {            // 4-wide tail (sanitized -> ZROW)
            uint2 cu = *reinterpret_cast<const uint2*>(&cols[nl * LSTR + j]);
            int s0 = (int)(cu.x & 0xffffu), s1 = (int)(cu.x >> 16);
            int s2 = (int)(cu.y & 0xffffu), s3 = (int)(cu.y >> 16);
            uint4 u0 = *reinterpret_cast<const uint4*>(hb + (size_t)s0 * 96 + c);
            uint4 u1 = *reinterpret_cast<const uint4*>(hb + (size_t)s1 * 96 + c);
            uint4 u2 = *reinterpret_cast<const uint4*>(hb + (size_t)s2 * 96 + c);
            uint4 u3 = *reinterpret_cast<const uint4*>(hb + (size_t)s3 * 96 + c);
            a0 += bf2f_lo(u0.x) + bf2f_lo(u1.x) + bf2f_lo(u2.x) + bf2f_lo(u3.x);
            a1 += bf2f_hi(u0.x) + bf2f_hi(u1.x) + bf2f_hi(u2.x) + bf2f_hi(u3.x);
            a2 += bf2f_lo(u0.y) + bf2f_lo(u1.y) + bf2f_lo(u2.y) + bf2f_lo(u3.y);
            a3 += bf2f_hi(u0.y) + bf2f_hi(u1.y) + bf2f_hi(u2.y) + bf2f_hi(u3.y);
            a4 += bf2f_lo(u0.z) + bf2f_lo(u1.z) + bf2f_lo(u2.z) + bf2f_lo(u3.z);
            a5 += bf2f_hi(u0.z) + bf2f_hi(u1.z) + bf2f_hi(u2.z) + bf2f_hi(u3.z);
            a6 += bf2f_lo(u0.w) + bf2f_lo(u1.w) + bf2f_lo(u2.w) + bf2f_lo(u3.w);
            a7 += bf2f_hi(u0.w) + bf2f_hi(u1.w) + bf2f_hi(u2.w) + bf2f_hi(u3.w);
        }
        float inv = (d > 0) ? 1.0f / (float)d : 0.0f;
        uint4 o;
        o.x = (unsigned)f2bf(a0 * inv) | ((unsigned)f2bf(a1 * inv) << 16);
        o.y = (unsigned)f2bf(a2 * inv) | ((unsigned)f2bf(a3 * inv) << 16);
        o.z = (unsigned)f2bf(a4 * inv) | ((unsigned)f2bf(a5 * inv) << 16);
        o.w = (unsigned)f2bf(a6 * inv) | ((unsigned)f2bf(a7 * inv) << 16);
        *reinterpret_cast<uint4*>(&Asm[nl][c]) = o;
    }
    __syncthreads();

    const int wave = t >> 6;
    const int lane = t & 63;
    const int m = lane & 15;
    const int kq = (lane >> 4) * 8;

    bf16x8 afr[6];
#pragma unroll
    for (int kk = 0; kk < 3; ++kk)
        afr[kk] = *reinterpret_cast<const bf16x8*>(&Asm[m][kq + kk * 32]);
    const unsigned short* hrow = hb + (size_t)(i0 + m) * 96 + kq;
#pragma unroll
    for (int kk = 0; kk < 3; ++kk)
        afr[3 + kk] = *reinterpret_cast<const bf16x8*>(hrow + kk * 32);

    if (Y2EP) __syncthreads();   // all afr loads done before Asm is re-staged

    const int r0 = (lane >> 4) * 4;
    for (int nt = wave; nt < NT; nt += 4) {
        f32x4 acc = {0.f, 0.f, 0.f, 0.f};
        const unsigned short* wrow = WT + (size_t)(nt * 16 + m) * 192 + kq;
#pragma unroll
        for (int kk = 0; kk < 6; ++kk) {
            bf16x8 bfr = *reinterpret_cast<const bf16x8*>(wrow + kk * 32);
            acc = __builtin_amdgcn_mfma_f32_16x16x32_bf16(afr[kk], bfr, acc, 0, 0, 0);
        }
        int colj = nt * 16 + m;
        float bv = bias[colj];
#pragma unroll
        for (int r = 0; r < 4; ++r) {
            float v = fmaxf(acc[r] + bv, 0.0f);
            unsigned short hv = f2bf(v);
            out_bf[(size_t)(i0 + r0 + r) * (16 * NT) + colj] = hv;
            if (Y2EP) Asm[r0 + r][colj] = hv;   // re-stage h2 tile for Y2 GEMM
        }
    }

    if (Y2EP) {
        __syncthreads();
        if (wave < 3) {
            bf16x8 a2[3];
#pragma unroll
            for (int kk = 0; kk < 3; ++kk)
                a2[kk] = *reinterpret_cast<const bf16x8*>(&Asm[m][kq + kk * 32]);
            f32x4 acc = {0.f, 0.f, 0.f, 0.f};
            const unsigned short* wrow = WT2l + (size_t)(wave * 16 + m) * 96 + kq;
#pragma unroll
            for (int kk = 0; kk < 3; ++kk) {
                bf16x8 bfr = *reinterpret_cast<const bf16x8*>(wrow + kk * 32);
                acc = __builtin_amdgcn_mfma_f32_16x16x32_bf16(a2[kk], bfr, acc, 0, 0, 0);
            }
            int colj2 = wave * 16 + m;
#pragma unroll
            for (int r = 0; r < 4; ++r)
                Y2b[(size_t)(i0 + r0 + r) * 48 + colj2] = f2bf(acc[r]);
        }
    }
}

// ---------------- final layer: gather Y2-mean (96B rows) + self MFMA ----------------
// Block = 16 nodes, 256 threads. Gather: 96 threads (6/node, 16B each) read
// Y2 rows -- HALF the loads/bytes of a 96-col gather. Mean goes to LDS f32.
// Self term h2 @ Wr2 via K=96 MFMA (waves 0..2); out = relu(self + mean + b).
__global__ __launch_bounds__(256) void fused_final(
    const unsigned short* __restrict__ hb,    // h2b [50001][96]
    const unsigned short* __restrict__ Y2b,   // [50001][48]
    const int* __restrict__ deg, const unsigned short* __restrict__ colu,
    const unsigned short* __restrict__ WT2r,  // [48][96] = Wr2^T
    const float* __restrict__ bias,           // [48]
    float* __restrict__ out_f) {              // [50000][48]
    __shared__ float Msm[16][56];
    __shared__ unsigned short cols[16 * LSTR];
    const int i0 = blockIdx.x * 16;
    const int t = threadIdx.x;

    // ---- stage + sanitize adjacency: 1024 ushorts, 4 per thread ----
    {
        int u4 = t * 4;
        int node = u4 >> 6;
        int slot = u4 & 63;
        uint2 v = *reinterpret_cast<const uint2*>(colu + (size_t)(i0 + node) * CAP + slot);
        int d = deg[i0 + node];
        unsigned int s0 = (slot + 0 < d) ? (v.x & 0xffffu) : ZROW;
        unsigned int s1 = (slot + 1 < d) ? (v.x >> 16)     : ZROW;
        unsigned int s2 = (slot + 2 < d) ? (v.y & 0xffffu) : ZROW;
        unsigned int s3 = (slot + 3 < d) ? (v.y >> 16)     : ZROW;
        uint2 o;
        o.x = s0 | (s1 << 16);
        o.y = s2 | (s3 << 16);
        *reinterpret_cast<uint2*>(&cols[node * LSTR + slot]) = o;
    }
    __syncthreads();

    if (t < 96) {
        const int nl = t / 6;
        const int c = (t - nl * 6) * 8;      // ushort col offset in 48-col row
        const int d = deg[i0 + nl];
        const int d8 = d & ~7;
        const int pd4 = (d + 3) & ~3;
        float a0 = 0.f, a1 = 0.f, a2 = 0.f, a3 = 0.f, a4 = 0.f, a5 = 0.f, a6 = 0.f, a7 = 0.f;
        int j = 0;
        for (; j < d8; j += 8) {
            uint4 cu = *reinterpret_cast<const uint4*>(&cols[nl * LSTR + j]);
            int s0 = (int)(cu.x & 0xffffu), s1 = (int)(cu.x >> 16);
            int s2 = (int)(cu.y & 0xffffu), s3 = (int)(cu.y >> 16);
            int s4 = (int)(cu.z & 0xffffu), s5 = (int)(cu.z >> 16);
            int s6 = (int)(cu.w & 0xffffu), s7 = (int)(cu.w >> 16);
            uint4 u0 = *reinterpret_cast<const uint4*>(Y2b + (size_t)s0 * 48 + c);
            uint4 u1 = *reinterpret_cast<const uint4*>(Y2b + (size_t)s1 * 48 + c);
            uint4 u2 = *reinterpret_cast<const uint4*>(Y2b + (size_t)s2 * 48 + c);
            uint4 u3 = *reinterpret_cast<const uint4*>(Y2b + (size_t)s3 * 48 + c);
            uint4 u4 = *reinterpret_cast<const uint4*>(Y2b + (size_t)s4 * 48 + c);
            uint4 u5 = *reinterpret_cast<const uint4*>(Y2b + (size_t)s5 * 48 + c);
            uint4 u6 = *reinterpret_cast<const uint4*>(Y2b + (size_t)s6 * 48 + c);
            uint4 u7 = *reinterpret_cast<const uint4*>(Y2b + (size_t)s7 * 48 + c);
            a0 += bf2f_lo(u0.x) + bf2f_lo(u1.x) + bf2f_lo(u2.x) + bf2f_lo(u3.x)
                + bf2f_lo(u4.x) + bf2f_lo(u5.x) + bf2f_lo(u6.x) + bf2f_lo(u7.x);
            a1 += bf2f_hi(u0.x) + bf2f_hi(u1.x) + bf2f_hi(u2.x) + bf2f_hi(u3.x)
                + bf2f_hi(u4.x) + bf2f_hi(u5.x) + bf2f_hi(u6.x) + bf2f_hi(u7.x);
            a2 += bf2f_lo(u0.y) + bf2f_lo(u1.y) + bf2f_lo(u2.y) + bf2f_lo(u3.y)
                + bf2f_lo(u4.y) + bf2f_lo(u5.y) + bf2f_lo(u6.y) + bf2f_lo(u7.y);
            a3 += bf2f_hi(u0.y) + bf2f_hi(u1.y) + bf2f_hi(u2.y) + bf2f_hi(u3.y)
                + bf2f_hi(u4.y) + bf2f_hi(u5.y) + bf2f_hi(u6.y) + bf2f_hi(u7.y);
            a4 += bf2f_lo(u0.z) + bf2f_lo(u1.z) + bf2f_lo(u2.z) + bf2f_lo(u3.z)
                + bf2f_lo(u4.z) + bf2f_lo(u5.z) + bf2f_lo(u6.z) + bf2f_lo(u7.z);
            a5 += bf2f_hi(u0.z) + bf2f_hi(u1.z) + bf2f_hi(u2.z) + bf2f_hi(u3.z)
                + bf2f_hi(u4.z) + bf2f_hi(u5.z) + bf2f_hi(u6.z) + bf2f_hi(u7.z);
            a6 += bf2f_lo(u0.w) + bf2f_lo(u1.w) + bf2f_lo(u2.w) + bf2f_lo(u3.w)
                + bf2f_lo(u4.w) + bf2f_lo(u5.w) + bf2f_lo(u6.w) + bf2f_lo(u7.w);
            a7 += bf2f_hi(u0.w) + bf2f_hi(u1.w) + bf2f_hi(u2.w) + bf2f_hi(u3.w)
                + bf2f_hi(u4.w) + bf2f_hi(u5.w) + bf2f_hi(u6.w) + bf2f_hi(u7.w);
        }
        for (; j < pd4; j += 4) {
            uint2 cu = *reinterpret_cast<const uint2*>(&cols[nl * LSTR + j]);
            int s0 = (int)(cu.x & 0xffffu), s1 = (int)(cu.x >> 16);
            int s2 = (int)(cu.y & 0xffffu), s3 = (int)(cu.y >> 16);
            uint4 u0 = *reinterpret_cast<const uint4*>(Y2b + (size_t)s0 * 48 + c);
            uint4 u1 = *reinterpret_cast<const uint4*>(Y2b + (size_t)s1 * 48 + c);
            uint4 u2 = *reinterpret_cast<const uint4*>(Y2b + (size_t)s2 * 48 + c);
            uint4 u3 = *reinterpret_cast<const uint4*>(Y2b + (size_t)s3 * 48 + c);
            a0 += bf2f_lo(u0.x) + bf2f_lo(u1.x) + bf2f_lo(u2.x) + bf2f_lo(u3.x);
            a1 += bf2f_hi(u0.x) + bf2f_hi(u1.x) + bf2f_hi(u2.x) + bf2f_hi(u3.x);
            a2 += bf2f_lo(u0.y) + bf2f_lo(u1.y) + bf2f_lo(u2.y) + bf2f_lo(u3.y);
            a3 += bf2f_hi(u0.y) + bf2f_hi(u1.y) + bf2f_hi(u2.y) + bf2f_hi(u3.y);
            a4 += bf2f_lo(u0.z) + bf2f_lo(u1.z) + bf2f_lo(u2.z) + bf2f_lo(u3.z);
            a5 += bf2f_hi(u0.z) + bf2f_hi(u1.z) + bf2f_hi(u2.z) + bf2f_hi(u3.z);
            a6 += bf2f_lo(u0.w) + bf2f_lo(u1.w) + bf2f_lo(u2.w) + bf2f_lo(u3.w);
            a7 += bf2f_hi(u0.w) + bf2f_hi(u1.w) + bf2f_hi(u2.w) + bf2f_hi(u3.w);
        }
        float inv = (d > 0) ? 1.0f / (float)d : 0.0f;
        float4 o0 = make_float4(a0 * inv, a1 * inv, a2 * inv, a3 * inv);
        float4 o1 = make_float4(a4 * inv, a5 * inv, a6 * inv, a7 * inv);
        *reinterpret_cast<float4*>(&Msm[nl][c]) = o0;
        *reinterpret_cast<float4*>(&Msm[nl][c + 4]) = o1;
    }
    __syncthreads();

    const int wave = t >> 6;
    const int lane = t & 63;
    const int m = lane & 15;
    const int kq = (lane >> 4) * 8;
    const int r0 = (lane >> 4) * 4;

    if (wave < 3) {
        bf16x8 afr[3];
        const unsigned short* hrow = hb + (size_t)(i0 + m) * 96 + kq;
#pragma unroll
        for (int kk = 0; kk < 3; ++kk)
            afr[kk] = *reinterpret_cast<const bf16x8*>(hrow + kk * 32);
        f32x4 acc = {0.f, 0.f, 0.f, 0.f};
        const unsigned short* wrow = WT2r + (size_t)(wave * 16 + m) * 96 + kq;
#pragma unroll
        for (int kk = 0; kk < 3; ++kk) {
            bf16x8 bfr = *reinterpret_cast<const bf16x8*>(wrow + kk * 32);
            acc = __builtin_amdgcn_mfma_f32_16x16x32_bf16(afr[kk], bfr, acc, 0, 0, 0);
        }
        int colj = wave * 16 + m;
        float bv = bias[colj];
#pragma unroll
        for (int r = 0; r < 4; ++r) {
            int row = r0 + r;
            float v = fmaxf(acc[r] + Msm[row][colj] + bv, 0.0f);
            out_f[(size_t)(i0 + row) * 48 + colj] = v;
        }
    }
}

extern "C" void kernel_launch(void* const* d_in, const int* in_sizes, int n_in,
                              void* d_out, int out_size, void* d_ws, size_t ws_size,
                              hipStream_t stream) {
    const float* x   = (const float*)d_in[0];
    const int*   ei  = (const int*)d_in[1];   // [2, E]: row0 = src, row1 = dst
    const float* Wl0 = (const float*)d_in[2];
    const float* Wr0 = (const float*)d_in[3];
    const float* b0  = (const float*)d_in[4];
    const float* Wl1 = (const float*)d_in[5];
    const float* Wr1 = (const float*)d_in[6];
    const float* b1  = (const float*)d_in[7];
    const float* Wl2 = (const float*)d_in[8];
    const float* Wr2 = (const float*)d_in[9];
    const float* b2  = (const float*)d_in[10];
    float* out = (float*)d_out;

    const int* src = ei;
    const int* dst = ei + NEDGES;

    // workspace layout (all offsets multiples of 64 B)
    char* p = (char*)d_ws;
    int* deg = (int*)p;                        p += (size_t)50176 * 4;        // 200 KB
    unsigned short* colu = (unsigned short*)p; p += (size_t)50176 * CAP * 2;  // 6.4 MB
    unsigned char* cnta = (unsigned char*)p;   p += (size_t)NBKT * EBA;       // 204800 B
    unsigned short* WT0 = (unsigned short*)p;  p += 96 * 192 * 2;
    unsigned short* WT1 = (unsigned short*)p;  p += 96 * 192 * 2;
    unsigned short* WT2l = (unsigned short*)p; p += 48 * 96 * 2;
    unsigned short* WT2r = (unsigned short*)p; p += 48 * 96 * 2;
    unsigned short* h0b = (unsigned short*)p;  p += (size_t)(NNODES + 1) * 96 * 2 + 64;
    unsigned short* h1b = (unsigned short*)p;  p += (size_t)(NNODES + 1) * 96 * 2 + 64;
    unsigned short* h2b = (unsigned short*)p;  p += (size_t)(NNODES + 1) * 96 * 2 + 64;
    unsigned short* Y2b = (unsigned short*)p;  p += (size_t)(NNODES + 1) * 48 * 2 + 64;

    // region (EBA*NBKT*SEGC*4 = 16.38 MB) aliases h1b+h2b (19.2 MB): region is
    // dead after build_b; h1b/h2b are first written by the layer kernels after.
    unsigned int* region = (unsigned int*)h1b;

    // ---- phase A: fine-bucket edges + converts (one grid, LDS atomics only) ----
    build_a<<<EBA + CB + WB + 1, 512, 0, stream>>>(
        src, dst, region, cnta, x, h0b,
        Wl0, Wr0, Wl1, Wr1, Wl2, Wr2, WT0, WT1, WT2l, WT2r);

    // ---- phase B: one bucket per block, LDS-atomic slotting, coalesced dump ----
    build_b<<<NBKB, 512, 0, stream>>>(region, cnta, deg, colu);

    // ---- layers ----
    const int LB = NNODES / 16;   // 3125 exact
    fused_layer<6, false><<<LB, 256, 0, stream>>>(h0b, deg, colu, WT0, b0, h1b,
                                                  nullptr, nullptr);
    fused_layer<6, true><<<LB, 256, 0, stream>>>(h1b, deg, colu, WT1, b1, h2b,
                                                 WT2l, Y2b);
    fused_final<<<LB, 256, 0, stream>>>(h2b, Y2b, deg, colu, WT2r, b2, out);
}